// Round 7
// baseline (87.828 us; speedup 1.0000x reference)
//
#include <hip/hip_runtime.h>
#include <math.h>

#define BN 1024   // batch
#define CN 512    // clusters
#define DN 256    // dims
#define ROWS 4    // batch rows per block (fused kernel)
#define WAVES 8   // k-split across waves
#define KC (DN / WAVES)   // 32 k per wave

// ws layout (floats): xs[BN*DN] | r[BN] | q[CN]
#define XS_OFF 0
#define R_OFF  (BN * DN)
#define Q_OFF  (R_OFF + BN)

// ---------------------------------------------------------------------------
// prep: a_d = attn_d / sum(attn);  xs[b,d] = a_d * x[b,d];
//       r[b] = sum_d a_d x^2;  q[c] = sum_d a_d w^2.
// grid BN+CN blocks x 256 threads (1 row each, attn sum redundant per block).
// ---------------------------------------------------------------------------
__launch_bounds__(256, 4)
__global__ void prep_kernel(const float* __restrict__ inp, const float* __restrict__ wd,
                            const float* __restrict__ attn, float* __restrict__ ws) {
    __shared__ float red[4];
    float* xs = ws + XS_OFF;
    float* r  = ws + R_OFF;
    float* q  = ws + Q_OFF;

    const int tid  = threadIdx.x;          // == d, 256 threads = DN
    const int lane = tid & 63;
    const int blk  = blockIdx.x;

    float av = attn[tid];
    float s = av;
    #pragma unroll
    for (int off = 32; off > 0; off >>= 1) s += __shfl_xor(s, off);
    if (lane == 0) red[tid >> 6] = s;
    __syncthreads();
    const float a = av / (red[0] + red[1] + red[2] + red[3]);

    float c;
    if (blk < BN) {
        const float x = inp[blk * DN + tid];
        xs[blk * DN + tid] = a * x;
        c = a * x * x;
    } else {
        const float w = wd[(blk - BN) * DN + tid];
        c = a * w * w;
    }
    #pragma unroll
    for (int off = 32; off > 0; off >>= 1) c += __shfl_xor(c, off);
    __syncthreads();                       // red[] reuse
    if (lane == 0) red[tid >> 6] = c;
    __syncthreads();
    if (tid == 0) {
        const float tot = red[0] + red[1] + red[2] + red[3];
        if (blk < BN) r[blk] = tot; else q[blk - BN] = tot;
    }
}

// ---------------------------------------------------------------------------
// fused: per block, 4 batch rows x ALL 512 clusters, K split across 8 waves.
// Lane owns 8 clusters c = lane + 64j (coalesced q/mask/w_assoc access).
// xs values are wave-uniform -> s_load (SGPR fma operand); w streamed from
// global (L2-hot). Partials combined via one 64 KB LDS pass; waves 0..3 then
// run the full double-softmax + readout for one row each, all in-wave.
// ---------------------------------------------------------------------------
#define NEG_INF_F (-1e30f)

__device__ __forceinline__ float waveMax(float v) {
    #pragma unroll
    for (int off = 32; off > 0; off >>= 1) v = fmaxf(v, __shfl_xor(v, off));
    return v;
}
__device__ __forceinline__ float waveSum(float v) {
    #pragma unroll
    for (int off = 32; off > 0; off >>= 1) v += __shfl_xor(v, off);
    return v;
}

__launch_bounds__(512, 1)
__global__ void fused_kernel(const float* __restrict__ ws, const float* __restrict__ wd,
                             const int* __restrict__ mask, const float* __restrict__ w_assoc,
                             float* __restrict__ y) {
    __shared__ float red[WAVES * 32 * 64];   // 64 KB: [z][v=r*8+j][lane]

    const int tid  = threadIdx.x;
    const int lane = tid & 63;
    const int wz   = __builtin_amdgcn_readfirstlane(tid >> 6);   // wave id = k-chunk
    const int b0   = blockIdx.x * ROWS;
    const int kbase = wz * KC;

    const float* xs = ws + XS_OFF;

    // per-lane w base pointers for 8 clusters (offsets folded to immediates)
    const float* wp[8];
    #pragma unroll
    for (int j = 0; j < 8; ++j)
        wp[j] = wd + (size_t)(lane + 64 * j) * DN + kbase;

    float acc[ROWS][8] = {};   // dot(xs_row, w_c) partials over this wave's k-chunk

    #pragma unroll
    for (int k4 = 0; k4 < KC / 4; ++k4) {
        // wave-uniform scalar loads: 4 rows x float4 of pre-scaled input
        float4 xv[ROWS];
        #pragma unroll
        for (int rr = 0; rr < ROWS; ++rr) {
            const int idx = __builtin_amdgcn_readfirstlane((b0 + rr) * DN + kbase + 4 * k4);
            xv[rr] = *(const float4*)&xs[idx];
        }
        #pragma unroll
        for (int j = 0; j < 8; ++j) {
            const float4 w4 = *(const float4*)(wp[j] + 4 * k4);
            #pragma unroll
            for (int rr = 0; rr < ROWS; ++rr) {
                float t = fmaf(xv[rr].x, w4.x, acc[rr][j]);
                t = fmaf(xv[rr].y, w4.y, t);
                t = fmaf(xv[rr].z, w4.z, t);
                acc[rr][j] = fmaf(xv[rr].w, w4.w, t);
            }
        }
    }

    // stage partials lane-contiguous (conflict-free b32)
    #pragma unroll
    for (int rr = 0; rr < ROWS; ++rr)
        #pragma unroll
        for (int j = 0; j < 8; ++j)
            red[(wz * 32 + rr * 8 + j) * 64 + lane] = acc[rr][j];
    __syncthreads();

    if (wz < ROWS) {
        const int rr = wz;                 // this wave finishes row b0+rr

        float dot[8] = {};
        #pragma unroll
        for (int z = 0; z < WAVES; ++z)
            #pragma unroll
            for (int j = 0; j < 8; ++j)
                dot[j] += red[(z * 32 + rr * 8 + j) * 64 + lane];

        const float rb = ws[R_OFF + b0 + rr];          // uniform s_load

        float t[8]; bool rec[8];
        #pragma unroll
        for (int j = 0; j < 8; ++j) {
            const int c = lane + 64 * j;
            const float wdist = fmaxf(rb + ws[Q_OFF + c] - 2.0f * dot[j], 0.0f);
            t[j] = sqrtf(wdist);
            rec[j] = mask[c] > 0;
        }

        // softmax #1: logits -3*t  (= BETA*log H / TEMP_COMP)
        float l1[8], lmax = NEG_INF_F;
        #pragma unroll
        for (int j = 0; j < 8; ++j) { l1[j] = rec[j] ? (-3.0f * t[j]) : NEG_INF_F; lmax = fmaxf(lmax, l1[j]); }
        const float mx1 = waveMax(lmax);
        float e1[8], lsum = 0.f;
        #pragma unroll
        for (int j = 0; j < 8; ++j) { e1[j] = rec[j] ? expf(l1[j] - mx1) : 0.f; lsum += e1[j]; }
        const float inv_s1 = 1.0f / waveSum(lsum);

        float competed[8];
        #pragma unroll
        for (int j = 0; j < 8; ++j) competed[j] = e1[j] * inv_s1 * expf(-t[j]);

        // softmax #2: logits competed / 0.1
        float l2[8]; lmax = NEG_INF_F;
        #pragma unroll
        for (int j = 0; j < 8; ++j) { l2[j] = rec[j] ? (competed[j] * 10.0f) : NEG_INF_F; lmax = fmaxf(lmax, l2[j]); }
        const float mx2 = waveMax(lmax);
        float e2[8]; lsum = 0.f;
        #pragma unroll
        for (int j = 0; j < 8; ++j) { e2[j] = rec[j] ? expf(l2[j] - mx2) : 0.f; lsum += e2[j]; }
        const float inv_s2 = 1.0f / waveSum(lsum);

        // readout y = 1.5 * (softwta @ w_assoc); w_assoc reads coalesced (8B/lane)
        float y0 = 0.f, y1 = 0.f;
        #pragma unroll
        for (int j = 0; j < 8; ++j) {
            const int c = lane + 64 * j;
            const float sw = e2[j] * inv_s2 * competed[j];
            const float2 wa = *(const float2*)&w_assoc[2 * c];
            y0 = fmaf(sw, wa.x, y0);
            y1 = fmaf(sw, wa.y, y1);
        }
        y0 = waveSum(y0);
        y1 = waveSum(y1);
        if (lane == 0) {
            float2 o = {1.5f * y0, 1.5f * y1};
            *(float2*)&y[(b0 + rr) * 2] = o;
        }
    }
}

extern "C" void kernel_launch(void* const* d_in, const int* in_sizes, int n_in,
                              void* d_out, int out_size, void* d_ws, size_t ws_size,
                              hipStream_t stream) {
    const float* inp     = (const float*)d_in[0];  // [B, D]
    const float* w_dist  = (const float*)d_in[1];  // [C, D]
    const float* attn    = (const float*)d_in[2];  // [D]
    const float* w_assoc = (const float*)d_in[3];  // [C, 2]
    const int*   mask    = (const int*)d_in[4];    // [C]
    float* out = (float*)d_out;                    // [B, 2]
    float* ws  = (float*)d_ws;                     // ~1.1 MB used

    prep_kernel<<<BN + CN, 256, 0, stream>>>(inp, w_dist, attn, ws);
    fused_kernel<<<BN / ROWS, 512, 0, stream>>>(ws, w_dist, mask, w_assoc, out);
}